// Round 10
// baseline (368.318 us; speedup 1.0000x reference)
//
#include <hip/hip_runtime.h>
#include <math.h>

#define B_    2
#define C_    128
#define N_    2048
#define HID_  512
#define HEADS_ 8
#define EPS_  1e-6f
#define NS_   0.2f
#define KSPLIT 8

typedef __attribute__((ext_vector_type(8))) short short8v;  // 8 bf16
typedef __attribute__((ext_vector_type(4))) float f32x4;
typedef unsigned short ush;
typedef unsigned int u32;

__device__ inline ush f2bf(float f) {
    unsigned u = __float_as_uint(f);
    u += 0x7FFF + ((u >> 16) & 1);          // round-to-nearest-even
    return (ush)(u >> 16);
}
__device__ inline float bf2f(ush u) { return __uint_as_float((u32)u << 16); }

// pack float -> (hi bf16 << 16) | lo bf16, with hi+lo ~ x to ~2^-17 rel
__device__ inline u32 splitpack(float x) {
    ush hi = f2bf(x);
    float hf = __uint_as_float((u32)hi << 16);
    ush lo = f2bf(x - hf);
    return ((u32)hi << 16) | (u32)lo;
}

__device__ inline void unpack16(const u32* buf, short8v& h0, short8v& h1,
                                short8v& l0, short8v& l1) {
    ush h[16], l[16];
    #pragma unroll
    for (int j = 0; j < 16; ++j) { u32 u = buf[j]; h[j] = (ush)(u >> 16); l[j] = (ush)(u & 0xffff); }
    h0 = *(short8v*)&h[0]; h1 = *(short8v*)&h[8];
    l0 = *(short8v*)&l[0]; l1 = *(short8v*)&l[8];
}

__device__ inline void unpack_hi(const u32* buf, short8v& h0, short8v& h1) {
    ush h[16];
    #pragma unroll
    for (int j = 0; j < 16; ++j) h[j] = (ush)(buf[j] >> 16);
    h0 = *(short8v*)&h[0]; h1 = *(short8v*)&h[8];
}

// ---------------------------------------------------------------------------
// vec_layernorm: writes fp32 y AND split plane ysp (round-8 verified version)
// ---------------------------------------------------------------------------
__global__ __launch_bounds__(256) void ln_kernel(const float* __restrict__ x,
        const float* __restrict__ gma, const float* __restrict__ bta,
        float* __restrict__ y, u32* __restrict__ ysp)
{
    __shared__ float norms[128][32];
    __shared__ float red1[8][32];
    __shared__ float red2[8][32];
    const int b  = blockIdx.y;
    const int n0 = blockIdx.x * 32;
    const int nn = threadIdx.x & 31;
    const int cg = threadIdx.x >> 5;

    float s1 = 0.f, s2 = 0.f;
    for (int it = 0; it < 16; ++it) {
        int c = it * 8 + cg;
        size_t base = ((size_t)(b * C_ + c) * 3) * N_ + n0 + nn;
        float x0 = x[base], x1 = x[base + N_], x2 = x[base + 2 * N_];
        float nr = sqrtf(x0 * x0 + x1 * x1 + x2 * x2 + EPS_);
        norms[c][nn] = nr;
        s1 += nr; s2 += nr * nr;
    }
    red1[cg][nn] = s1; red2[cg][nn] = s2;
    __syncthreads();
    float S1 = 0.f, S2 = 0.f;
    #pragma unroll
    for (int g = 0; g < 8; ++g) { S1 += red1[g][nn]; S2 += red2[g][nn]; }
    float mu   = S1 * (1.f / 128.f);
    float var  = S2 * (1.f / 128.f) - mu * mu;
    float rstd = rsqrtf(var + EPS_);

    for (int it = 0; it < 16; ++it) {
        int c = it * 8 + cg;
        float nr = norms[c][nn];
        float ln = (nr - mu) * rstd * gma[c] + bta[c];
        float sc = ln / (nr + EPS_);
        size_t base = ((size_t)(b * C_ + c) * 3) * N_ + n0 + nn;
        float y0 = x[base] * sc, y1 = x[base + N_] * sc, y2 = x[base + 2 * N_] * sc;
        y[base]          = y0;
        y[base + N_]     = y1;
        y[base + 2 * N_] = y2;
        ysp[base]          = splitpack(y0);
        ysp[base + N_]     = splitpack(y1);
        ysp[base + 2 * N_] = splitpack(y2);
    }
}

// ---------------------------------------------------------------------------
// weight split-conversion: 15 weights, one launch (with optional pre-scale)
// ---------------------------------------------------------------------------
struct WCArgs { const float* src[15]; u32* dst[15]; int n[15]; float scale[15]; };
__global__ __launch_bounds__(256) void wconv_kernel(WCArgs a)
{
    const int w = blockIdx.y;
    const int i = blockIdx.x * 256 + threadIdx.x;
    if (i < a.n[w]) a.dst[w][i] = splitpack(a.src[w][i] * a.scale[w]);
}

// ---------------------------------------------------------------------------
// bf16 MFMA GEMM core. SPLIT=true: Wh·Xh + Wh·Xl + Wl·Xh (fp32-quality).
// SPLIT=false: Wh·Xh only. 64x64 tile, K-step 64, 4 waves. LDS XOR-swizzled.
// XMODE 0: X[(b*K + c)*M + m]   XMODE 1: X[((b*N+n)*3+t)*K + c], m = t*N+n
// OMODE 0: fp32 (+Z)  1: split u32  2: both  3: bf16  4: qkv (V bf16 + Q/K
//   key-major transposed to Ytr[plane][n][64] with d = cl*3+t)
// ---------------------------------------------------------------------------
template <int XMODE, int OMODE, bool SPLIT>
__device__ __forceinline__ void gemm_tile(
    const u32* __restrict__ Wsp, int wstride,
    const u32* __restrict__ Xsp, int K,
    const float* __restrict__ Z, float* __restrict__ Y, u32* __restrict__ Ysp,
    ush* __restrict__ Ybf, ush* __restrict__ Ytr,
    int b, int m0, int o0loc, int oglob, int Ostr,
    ush (*Wh)[64], ush (*Wl)[64], ush (*Xh)[64], ush (*Xl)[64])
{
    const int M = 3 * N_;
    const int tid = threadIdx.x;
    const int lane = tid & 63, wv = tid >> 6;
    const int col = lane & 15, grp = lane >> 4;
    const int wo = wv >> 1, wm = wv & 1;

    f32x4 acc[2][2];
    #pragma unroll
    for (int i = 0; i < 2; ++i)
        #pragma unroll
        for (int j = 0; j < 2; ++j) { f32x4 z = {0.f,0.f,0.f,0.f}; acc[i][j] = z; }

    for (int kk = 0; kk < K; kk += 64) {
        // ---- stage W tile (64 o x 64 k) ----
        {
            const int o = tid >> 2, kg = tid & 3;
            const u32* src = Wsp + (size_t)(o0loc + o) * wstride + kk + kg * 16;
            u32 buf[16];
            #pragma unroll
            for (int j = 0; j < 4; ++j) *(uint4*)&buf[j * 4] = *(const uint4*)(src + j * 4);
            const int s0 = ((kg * 2)     ^ (o & 7)) << 3;
            const int s1 = ((kg * 2 + 1) ^ (o & 7)) << 3;
            if (SPLIT) {
                short8v h0, h1, l0, l1; unpack16(buf, h0, h1, l0, l1);
                *(short8v*)&Wh[o][s0] = h0; *(short8v*)&Wh[o][s1] = h1;
                *(short8v*)&Wl[o][s0] = l0; *(short8v*)&Wl[o][s1] = l1;
            } else {
                short8v h0, h1; unpack_hi(buf, h0, h1);
                *(short8v*)&Wh[o][s0] = h0; *(short8v*)&Wh[o][s1] = h1;
            }
        }
        // ---- stage X tile (64 k x 64 m), stored transposed Xs[m][k] ----
        if (XMODE == 0) {
            const int m = lane, kq = wv;
            const u32* src = Xsp + ((size_t)b * K + kk + kq * 16) * M + m0 + m;
            u32 buf[16];
            #pragma unroll
            for (int j = 0; j < 16; ++j) buf[j] = src[(size_t)j * M];
            const int s0 = ((kq * 2)     ^ (m & 7)) << 3;
            const int s1 = ((kq * 2 + 1) ^ (m & 7)) << 3;
            if (SPLIT) {
                short8v h0, h1, l0, l1; unpack16(buf, h0, h1, l0, l1);
                *(short8v*)&Xh[m][s0] = h0; *(short8v*)&Xh[m][s1] = h1;
                *(short8v*)&Xl[m][s0] = l0; *(short8v*)&Xl[m][s1] = l1;
            } else {
                short8v h0, h1; unpack_hi(buf, h0, h1);
                *(short8v*)&Xh[m][s0] = h0; *(short8v*)&Xh[m][s1] = h1;
            }
        } else {
            const int m = tid >> 2, kg = tid & 3;
            const int mg = m0 + m;
            const int n = mg & (N_ - 1), t = mg >> 11;
            const u32* src = Xsp + ((size_t)(b * N_ + n) * 3 + t) * K + kk + kg * 16;
            u32 buf[16];
            #pragma unroll
            for (int j = 0; j < 4; ++j) *(uint4*)&buf[j * 4] = *(const uint4*)(src + j * 4);
            const int s0 = ((kg * 2)     ^ (m & 7)) << 3;
            const int s1 = ((kg * 2 + 1) ^ (m & 7)) << 3;
            if (SPLIT) {
                short8v h0, h1, l0, l1; unpack16(buf, h0, h1, l0, l1);
                *(short8v*)&Xh[m][s0] = h0; *(short8v*)&Xh[m][s1] = h1;
                *(short8v*)&Xl[m][s0] = l0; *(short8v*)&Xl[m][s1] = l1;
            } else {
                short8v h0, h1; unpack_hi(buf, h0, h1);
                *(short8v*)&Xh[m][s0] = h0; *(short8v*)&Xh[m][s1] = h1;
            }
        }
        __syncthreads();
        // ---- MFMAs per K-step: 8 (hi-only) or 24 (split) ----
        #pragma unroll
        for (int kc = 0; kc < 2; ++kc) {
            const int sk = ((kc * 4 + grp) ^ (col & 7)) << 3;
            short8v ah0 = *(const short8v*)&Wh[wo * 32 + col][sk];
            short8v ah1 = *(const short8v*)&Wh[wo * 32 + 16 + col][sk];
            short8v xh0 = *(const short8v*)&Xh[wm * 32 + col][sk];
            short8v xh1 = *(const short8v*)&Xh[wm * 32 + 16 + col][sk];
            acc[0][0] = __builtin_amdgcn_mfma_f32_16x16x32_bf16(ah0, xh0, acc[0][0], 0, 0, 0);
            acc[0][1] = __builtin_amdgcn_mfma_f32_16x16x32_bf16(ah0, xh1, acc[0][1], 0, 0, 0);
            acc[1][0] = __builtin_amdgcn_mfma_f32_16x16x32_bf16(ah1, xh0, acc[1][0], 0, 0, 0);
            acc[1][1] = __builtin_amdgcn_mfma_f32_16x16x32_bf16(ah1, xh1, acc[1][1], 0, 0, 0);
            if (SPLIT) {
                short8v al0 = *(const short8v*)&Wl[wo * 32 + col][sk];
                short8v al1 = *(const short8v*)&Wl[wo * 32 + 16 + col][sk];
                short8v xl0 = *(const short8v*)&Xl[wm * 32 + col][sk];
                short8v xl1 = *(const short8v*)&Xl[wm * 32 + 16 + col][sk];
                acc[0][0] = __builtin_amdgcn_mfma_f32_16x16x32_bf16(ah0, xl0, acc[0][0], 0, 0, 0);
                acc[0][1] = __builtin_amdgcn_mfma_f32_16x16x32_bf16(ah0, xl1, acc[0][1], 0, 0, 0);
                acc[1][0] = __builtin_amdgcn_mfma_f32_16x16x32_bf16(ah1, xl0, acc[1][0], 0, 0, 0);
                acc[1][1] = __builtin_amdgcn_mfma_f32_16x16x32_bf16(ah1, xl1, acc[1][1], 0, 0, 0);
                acc[0][0] = __builtin_amdgcn_mfma_f32_16x16x32_bf16(al0, xh0, acc[0][0], 0, 0, 0);
                acc[0][1] = __builtin_amdgcn_mfma_f32_16x16x32_bf16(al0, xh1, acc[0][1], 0, 0, 0);
                acc[1][0] = __builtin_amdgcn_mfma_f32_16x16x32_bf16(al1, xh0, acc[1][0], 0, 0, 0);
                acc[1][1] = __builtin_amdgcn_mfma_f32_16x16x32_bf16(al1, xh1, acc[1][1], 0, 0, 0);
            }
        }
        __syncthreads();
    }
    // ---- epilogue ----
    #pragma unroll
    for (int of = 0; of < 2; ++of) {
        #pragma unroll
        for (int r = 0; r < 4; ++r) {
            const int o = oglob + wo * 32 + of * 16 + grp * 4 + r;
            #pragma unroll
            for (int mf = 0; mf < 2; ++mf) {
                const int mloc = m0 + wm * 32 + mf * 16 + col;
                const size_t idx = ((size_t)b * Ostr + o) * M + mloc;
                float v = acc[of][mf][r];
                if (OMODE == 0 || OMODE == 2) {
                    if (Z) v += Z[idx];
                    Y[idx] = v;
                }
                if (OMODE == 1 || OMODE == 2) Ysp[idx] = splitpack(v);
                if (OMODE == 3) Ybf[idx] = f2bf(v);
                if (OMODE == 4) {
                    ush bv = f2bf(v);
                    if (o >= 256) {
                        Ybf[idx] = bv;            // V: channel-major
                    } else {
                        int cl = o & 15, hh = (o >> 4) & 7, isK = (o >> 7) & 1;
                        int t = mloc >> 11, n = mloc & (N_ - 1);
                        int d = cl * 3 + t;
                        int plane = isK * 16 + b * 8 + hh;
                        Ytr[((size_t)plane * N_ + n) * 64 + d] = bv;
                    }
                }
            }
        }
    }
}

template <int XMODE, int OMODE, bool SPLIT>
__global__ __launch_bounds__(256) void gemm_kernel2(
    const u32* __restrict__ Wsp, int wstride,
    const u32* __restrict__ Xsp,
    const float* __restrict__ Z,
    float* __restrict__ Y, u32* __restrict__ Ysp,
    int Ostr, int obase, int K)
{
    if (SPLIT) {
        __shared__ __align__(16) ush Wh[64][64];
        __shared__ __align__(16) ush Wl[64][64];
        __shared__ __align__(16) ush Xh[64][64];
        __shared__ __align__(16) ush Xl[64][64];
        gemm_tile<XMODE, OMODE, true>(Wsp, wstride, Xsp, K, Z, Y, Ysp, nullptr, nullptr,
                                blockIdx.z, blockIdx.x * 64,
                                blockIdx.y * 64, obase + blockIdx.y * 64, Ostr,
                                Wh, Wl, Xh, Xl);
    } else {
        __shared__ __align__(16) ush Wh[64][64];
        __shared__ __align__(16) ush Xh[64][64];
        gemm_tile<XMODE, OMODE, false>(Wsp, wstride, Xsp, K, Z, Y, Ysp, nullptr, nullptr,
                                blockIdx.z, blockIdx.x * 64,
                                blockIdx.y * 64, obase + blockIdx.y * 64, Ostr,
                                Wh, nullptr, Xh, nullptr);
    }
}

struct QKVArgs {
    const u32* W0; const u32* W1; const u32* W2;
    const u32* X0; const u32* X1; const u32* X2;
};

// fused Q/K/V projections (hi-only): V -> channel-major bf16 qkvb;
// Q,K -> key-major transposed qktb (d padded to 64, pre-zeroed)
__global__ __launch_bounds__(256) void qkv_kernel(QKVArgs A, ush* __restrict__ Ybf,
                                                  ush* __restrict__ Ytr)
{
    __shared__ __align__(16) ush Wh[64][64];
    __shared__ __align__(16) ush Xh[64][64];
    const int wi = blockIdx.y >> 1;
    const u32* W = wi == 0 ? A.W0 : (wi == 1 ? A.W1 : A.W2);
    const u32* X = wi == 0 ? A.X0 : (wi == 1 ? A.X1 : A.X2);
    gemm_tile<0, 4, false>(W, 128, X, 128, nullptr, nullptr, nullptr, Ybf, Ytr,
                    blockIdx.z, blockIdx.x * 64,
                    (blockIdx.y & 1) * 64, blockIdx.y * 64, 384,
                    Wh, nullptr, Xh, nullptr);
}

// fused Wo (XMODE0, y=0,1) + We (XMODE1, y=2,3) -> f12 split (Ostr 256)
__global__ __launch_bounds__(256) void wowe_kernel(
    const u32* __restrict__ Wo, const u32* __restrict__ ao,
    const u32* __restrict__ We, const u32* __restrict__ gb,
    u32* __restrict__ f12)
{
    __shared__ __align__(16) ush Wh[64][64];
    __shared__ __align__(16) ush Xh[64][64];
    const int y = blockIdx.y;
    if (y < 2)
        gemm_tile<0, 1, false>(Wo, 128, ao, 128, nullptr, nullptr, f12, nullptr, nullptr,
                        blockIdx.z, blockIdx.x * 64, y * 64, y * 64, 256,
                        Wh, nullptr, Xh, nullptr);
    else
        gemm_tile<1, 1, false>(We, 256, gb, 256, nullptr, nullptr, f12, nullptr, nullptr,
                        blockIdx.z, blockIdx.x * 64, (y - 2) * 64, 128 + (y - 2) * 64, 256,
                        Wh, nullptr, Xh, nullptr);
}

// ---------------------------------------------------------------------------
// barrier-free split-K flash attention, XCD-chunked 1D grid (2048 blocks).
// Each XCD owns 4 complete (bh,zz) groups -> per-XCD working set ~1.9MB
// fits the 4MB L2. Each WAVE independent: 32 queries x 256-key slice.
// ---------------------------------------------------------------------------
__global__ __launch_bounds__(256) void attn_mfma_kernel(
    const ush* __restrict__ qkvb, const ush* __restrict__ qktb,
    ush* __restrict__ pacc, float* __restrict__ pml)
{
    __shared__ __align__(16) ush Pl[4][2][16][64];   // 16 KB

    // XCD-chunked decode: flat%8 = XCD (de-facto round-robin assignment)
    const int flat = blockIdx.x;
    const int xcd  = flat & 7;
    const int slot = flat >> 3;          // 0..255
    const int gid  = xcd * 4 + (slot >> 6);   // 0..31, 4 groups per XCD
    const int q32  = slot & 63;
    const int bh   = gid & 15;
    const int zz   = gid >> 4;           // 0..1

    const int b = bh >> 3, h = bh & 7;
    const int n0 = q32 * 32;
    const int tid = threadIdx.x;
    const int lane = tid & 63, wv = tid >> 6;
    const int col = lane & 15, grp = lane >> 4;
    const int c7  = col & 7;
    const int kz  = zz * 4 + wv;
    const int ks0 = kz * (N_ / KSPLIT);

    const ush* Qtb = qktb + (size_t)bh * N_ * 64;
    const ush* Ktb = qktb + (size_t)(16 + bh) * N_ * 64;
    const ush* Vb  = qkvb + (size_t)(b * 384 + 256 + h * 16) * 3 * N_;

    short8v qf[2][2];
    #pragma unroll
    for (int qi = 0; qi < 2; ++qi) {
        const ush* qr = Qtb + (size_t)(n0 + qi * 16 + col) * 64 + grp * 8;
        qf[qi][0] = *(const short8v*)qr;
        qf[qi][1] = *(const short8v*)(qr + 32);
    }

    f32x4 acc[2][3];
    #pragma unroll
    for (int qi = 0; qi < 2; ++qi)
        #pragma unroll
        for (int db = 0; db < 3; ++db) { f32x4 z = {0.f,0.f,0.f,0.f}; acc[qi][db] = z; }
    float m_i[2] = {0.f, 0.f};
    float l_l[2] = {0.f, 0.f};     // per-lane partial sums

    const int NT = (N_ / KSPLIT) / 64;    // 4 tiles of 64 keys
    for (int mt = 0; mt < NT; ++mt) {
        const int m0 = ks0 + mt * 64;

        // K fragments: contiguous 16B loads from transposed buffer
        short8v ka[4][2];
        #pragma unroll
        for (int kb = 0; kb < 4; ++kb) {
            const ush* kr = Ktb + (size_t)(m0 + kb * 16 + col) * 64 + grp * 8;
            ka[kb][0] = *(const short8v*)kr;
            ka[kb][1] = *(const short8v*)(kr + 32);
        }
        // V fragments
        short8v vf[2][3];
        #pragma unroll
        for (int hh = 0; hh < 2; ++hh)
            #pragma unroll
            for (int db = 0; db < 3; ++db)
                vf[hh][db] = *(const short8v*)(Vb + (size_t)(db * 16 + col) * N_ + m0 + hh * 32 + grp * 8);

        // ---- QK^T (swapped): sf[qi][kb] rows = keys, col = query ----
        f32x4 sf[2][4];
        __builtin_amdgcn_s_setprio(1);
        #pragma unroll
        for (int qi = 0; qi < 2; ++qi)
            #pragma unroll
            for (int kb = 0; kb < 4; ++kb) {
                f32x4 z = {0.f, 0.f, 0.f, 0.f};
                z = __builtin_amdgcn_mfma_f32_16x16x32_bf16(ka[kb][0], qf[qi][0], z, 0, 0, 0);
                z = __builtin_amdgcn_mfma_f32_16x16x32_bf16(ka[kb][1], qf[qi][1], z, 0, 0, 0);
                sf[qi][kb] = z;
            }
        __builtin_amdgcn_s_setprio(0);

        // ---- exp with current (lazy) max; P -> per-wave LDS ----
        #pragma unroll
        for (int qi = 0; qi < 2; ++qi) {
            float psum = 0.f;
            #pragma unroll
            for (int kb = 0; kb < 4; ++kb) {
                float e0 = __expf(sf[qi][kb][0] - m_i[qi]);
                float e1 = __expf(sf[qi][kb][1] - m_i[qi]);
                float e2 = __expf(sf[qi][kb][2] - m_i[qi]);
                float e3 = __expf(sf[qi][kb][3] - m_i[qi]);
                psum += (e0 + e1) + (e2 + e3);
                u32 r0, r1;
                asm("v_cvt_pk_bf16_f32 %0, %1, %2" : "=v"(r0) : "v"(e0), "v"(e1));
                asm("v_cvt_pk_bf16_f32 %0, %1, %2" : "=v"(r1) : "v"(e2), "v"(e3));
                const int un = (4 * kb + grp) ^ (c7 << 1);
                uint2 pk2; pk2.x = r0; pk2.y = r1;
                *(uint2*)&Pl[wv][qi][col][un << 2] = pk2;
            }
            l_l[qi] += psum;
        }

        // ---- PV ----
        __builtin_amdgcn_s_setprio(1);
        #pragma unroll
        for (int qi = 0; qi < 2; ++qi)
            #pragma unroll
            for (int hh = 0; hh < 2; ++hh) {
                const int ur = (8 * hh + 2 * grp) ^ (c7 << 1);
                short8v pf = *(const short8v*)&Pl[wv][qi][col][ur << 2];
                #pragma unroll
                for (int db = 0; db < 3; ++db)
                    acc[qi][db] = __builtin_amdgcn_mfma_f32_16x16x32_bf16(vf[hh][db], pf, acc[qi][db], 0, 0, 0);
            }
        __builtin_amdgcn_s_setprio(0);

        // ---- post-PV lazy max update ----
        #pragma unroll
        for (int qi = 0; qi < 2; ++qi) {
            float pmax = -1e30f;
            #pragma unroll
            for (int kb = 0; kb < 4; ++kb)
                #pragma unroll
                for (int r = 0; r < 4; ++r) pmax = fmaxf(pmax, sf[qi][kb][r]);
            pmax = fmaxf(pmax, __shfl_xor(pmax, 16, 64));
            pmax = fmaxf(pmax, __shfl_xor(pmax, 32, 64));
            if (!__all(pmax - m_i[qi] <= 8.0f)) {
                float mnew = fmaxf(m_i[qi], pmax);
                float sc = __expf(m_i[qi] - mnew);
                l_l[qi] *= sc;
                #pragma unroll
                for (int db = 0; db < 3; ++db) {
                    acc[qi][db][0] *= sc; acc[qi][db][1] *= sc;
                    acc[qi][db][2] *= sc; acc[qi][db][3] *= sc;
                }
                m_i[qi] = mnew;
            }
        }
    }

    // ---- partial epilogue ----
    const int ntile = q32 >> 1, qh = q32 & 1;
    const size_t pb = (size_t)(kz * 16 + bh) * 32 + ntile;
    #pragma unroll
    for (int qi = 0; qi < 2; ++qi) {
        float l = l_l[qi];
        l += __shfl_xor(l, 16, 64);
        l += __shfl_xor(l, 32, 64);
        const int q = qh * 32 + qi * 16 + col;
        #pragma unroll
        for (int db = 0; db < 3; ++db)
            #pragma unroll
            for (int r = 0; r < 4; ++r) {
                int d = db * 16 + grp * 4 + r;
                pacc[pb * 3072 + d * 64 + q] = f2bf(acc[qi][db][r]);
            }
        if (grp == 0) {
            pml[pb * 128 + q]      = m_i[qi];
            pml[pb * 128 + 64 + q] = l;
        }
    }
}

// ---------------------------------------------------------------------------
// split-K reduce: combine KSPLIT partials -> split u32 output
// ---------------------------------------------------------------------------
__global__ __launch_bounds__(256) void attn_reduce_kernel(
    const ush* __restrict__ pacc, const float* __restrict__ pml,
    u32* __restrict__ out_sp)
{
    const int nt = blockIdx.x, bh = blockIdx.y;
    const int b = bh >> 3, h = bh & 7;
    const int tid = threadIdx.x;
    const int q = tid & 63, dg = tid >> 6;

    size_t pb[KSPLIT];
    float m[KSPLIT], l[KSPLIT];
    #pragma unroll
    for (int kz = 0; kz < KSPLIT; ++kz) {
        pb[kz] = (size_t)(kz * 16 + bh) * 32 + nt;
        m[kz] = pml[pb[kz] * 128 + q];
        l[kz] = pml[pb[kz] * 128 + 64 + q];
    }
    float ms = -1e30f;
    #pragma unroll
    for (int kz = 0; kz < KSPLIT; ++kz) ms = fmaxf(ms, m[kz]);
    float w[KSPLIT], ls = 0.f;
    #pragma unroll
    for (int kz = 0; kz < KSPLIT; ++kz) { w[kz] = __expf(m[kz] - ms); ls += l[kz] * w[kz]; }
    const float inv = 1.f / ls;

    const size_t hb = ((size_t)(b * C_ + h * 16)) * 3 * N_;
    #pragma unroll
    for (int j = 0; j < 12; ++j) {
        int d = dg * 12 + j;
        float o = 0.f;
        #pragma unroll
        for (int kz = 0; kz < KSPLIT; ++kz)
            o += bf2f(pacc[pb[kz] * 3072 + d * 64 + q]) * w[kz];
        out_sp[hb + (size_t)d * N_ + nt * 64 + q] = splitpack(o * inv);
    }
}

// ---------------------------------------------------------------------------
// transpose (B,C,3,N) -> (B,N,3,C) fp32
// ---------------------------------------------------------------------------
__global__ __launch_bounds__(256) void transpose_kernel(const float* __restrict__ x,
                                                        float* __restrict__ y)
{
    __shared__ float tile[32][33];
    const int z = blockIdx.z;
    const int b = z / 3, t = z % 3;
    const int n0 = blockIdx.x * 32, c0 = blockIdx.y * 32;
    const int tx = threadIdx.x & 31, ty = threadIdx.x >> 5;
    #pragma unroll
    for (int p = 0; p < 4; ++p) {
        int c = c0 + ty + p * 8;
        tile[ty + p * 8][tx] = x[((size_t)(b * C_ + c) * 3 + t) * N_ + n0 + tx];
    }
    __syncthreads();
    #pragma unroll
    for (int p = 0; p < 4; ++p) {
        int n = n0 + ty + p * 8;
        y[((size_t)(b * N_ + n) * 3 + t) * C_ + c0 + tx] = tile[tx][ty + p * 8];
    }
}

// ---------------------------------------------------------------------------
// graph attention: fp32 in (B,N,3,C), split u32 edge buffer out
// ---------------------------------------------------------------------------
__global__ __launch_bounds__(256) void graph_kernel(
    const float* __restrict__ tq, const float* __restrict__ tv,
    const int* __restrict__ idx, u32* __restrict__ g)
{
    __shared__ float center[384];
    __shared__ float sd[16];
    __shared__ int nbr_i[16];
    const int b = blockIdx.y, n = blockIdx.x;
    const int tid = threadIdx.x;
    const float* qrow = tq + (size_t)(b * N_ + n) * 384;
    for (int e = tid; e < 384; e += 256) center[e] = qrow[e];
    if (tid < 16) nbr_i[tid] = idx[(size_t)(b * N_ + n) * 16 + tid];
    __syncthreads();

    const int lane = tid & 63, wv = tid >> 6;
    for (int kk = 0; kk < 4; ++kk) {
        int k = wv * 4 + kk;
        const float* vrow = tv + ((size_t)b * N_ + nbr_i[k]) * 384;
        float p = 0.f;
        #pragma unroll
        for (int jj = 0; jj < 6; ++jj) {
            int e = lane + jj * 64;
            p += center[e] * vrow[e];
        }
        #pragma unroll
        for (int off = 32; off; off >>= 1) p += __shfl_down(p, off, 64);
        if (lane == 0) sd[k] = p * 0.05103103630798288f;
    }
    __syncthreads();

    float mx = -1e30f;
    #pragma unroll
    for (int k = 0; k < 16; ++k) mx = fmaxf(mx, sd[k]);
    float a[16]; float ssum = 0.f;
    #pragma unroll
    for (int k = 0; k < 16; ++k) { a[k] = __expf(sd[k] - mx); ssum += a[k]; }
    float inv = 1.f / ssum;

    for (int e = tid; e < 384; e += 256) {
        float accv = 0.f;
        #pragma unroll
        for (int k = 0; k < 16; ++k)
            accv += a[k] * tv[((size_t)b * N_ + nbr_i[k]) * 384 + e];
        accv *= inv;
        float ce = center[e];
        int t = e >> 7, c = e & 127;
        size_t gb = ((size_t)(b * N_ + n) * 3 + t) * 256;
        g[gb + c]       = splitpack(accv - ce);
        g[gb + 128 + c] = splitpack(ce);
    }
}

// ---------------------------------------------------------------------------
// vn_leaky: fp32 x,d in -> split u32 out
// ---------------------------------------------------------------------------
__global__ __launch_bounds__(256) void leaky_kernel(const float* __restrict__ x,
                                                    const float* __restrict__ d,
                                                    u32* __restrict__ y)
{
    size_t p = (size_t)blockIdx.x * 256 + threadIdx.x;
    size_t bh = p / N_, n = p % N_;
    size_t base = bh * 3 * N_ + n;
    float x0 = x[base], x1 = x[base + N_], x2 = x[base + 2 * N_];
    float d0 = d[base], d1 = d[base + N_], d2 = d[base + 2 * N_];
    float dot = x0 * d0 + x1 * d1 + x2 * d2;
    float dsq = d0 * d0 + d1 * d1 + d2 * d2;
    float f = dot / (dsq + EPS_);
    bool pos = dot >= 0.f;
    float y0 = pos ? x0 : x0 - f * d0;
    float y1 = pos ? x1 : x1 - f * d1;
    float y2 = pos ? x2 : x2 - f * d2;
    y[base]          = splitpack(NS_ * x0 + (1.f - NS_) * y0);
    y[base + N_]     = splitpack(NS_ * x1 + (1.f - NS_) * y1);
    y[base + 2 * N_] = splitpack(NS_ * x2 + (1.f - NS_) * y2);
}

// ---------------------------------------------------------------------------
extern "C" void kernel_launch(void* const* d_in, const int* in_sizes, int n_in,
                              void* d_out, int out_size, void* d_ws, size_t ws_size,
                              hipStream_t stream)
{
    const float* q_in = (const float*)d_in[0];
    const float* v_in = (const float*)d_in[1];
    const int*   idx_s = (const int*)d_in[4];
    const int*   idx_c = (const int*)d_in[5];
    const float* g1 = (const float*)d_in[6];
    const float* b1 = (const float*)d_in[7];
    const float* g2 = (const float*)d_in[8];
    const float* b2 = (const float*)d_in[9];
    const float* gq = (const float*)d_in[10];
    const float* bq = (const float*)d_in[11];
    const float* gv = (const float*)d_in[12];
    const float* bv = (const float*)d_in[13];
    float* out = (float*)d_out;
    float* ws  = (float*)d_ws;

    const size_t S1 = (size_t)B_ * C_ * 3 * N_; // 1572864 elems
    float* nx    = ws;                 // 0
    float* nv    = ws + S1;            // 1
    u32*   nx_s  = (u32*)(ws + 2*S1);  // 2  (dead after qkv -> reused as pml)
    u32*   nv_s  = (u32*)(ws + 3*S1);  // 3
    ush*   qkvb  = (ush*)(ws + 4*S1);  // 4-5.5 (b,384,3N bf16; V region used)
    ush*   qktb  = (ush*)(ws + 5*S1) + S1;  // 5.5-6.84: 32 planes x 2048 x 64 bf16
    u32*   ao_s  = (u32*)(ws + 7*S1);  // 7
    u32*   f12_s = (u32*)(ws + 8*S1);  // 8-9
    u32*   gbuf_s= (u32*)(ws + 10*S1); // 10-11
    float* qa    = ws + 12*S1;         // 12
    float* qb    = ws + 13*S1;         // 13
    float* t1    = ws + 14*S1;         // 14
    float* t2    = ws + 15*S1;         // 15
    u32*   wsp   = (u32*)(ws + 16*S1); // 16
    // split-K attention partials (live only attn->reduce; freed before graph/WoWe)
    ush*   pacc  = (ush*)(ws + 8*S1);  // 8-11: 4096*3072*2B = 25.2MB
    float* pml   = (float*)(ws + 2*S1);// 2:    4096*128*4B  = 2.1MB
    // phase C aliases:
    float* hd    = ws;                 // 0-3
    float* h1    = ws + 4*S1;          // 4-7
    u32*   h1_s  = (u32*)(ws + 8*S1);  // 8-11

    const int wn[15]  = {16384,16384,16384,16384,32768,32768,
                         16384,16384,16384,16384,32768,32768,
                         65536,262144,65536};
    u32* wd[15];
    {
        int off = 0;
        for (int i = 0; i < 15; ++i) { wd[i] = wsp + off; off += wn[i]; }
    }
    u32 *Wq_s = wd[0], *Wk_s = wd[1], *Wv_s = wd[2], *Wo_s = wd[3], *We_s = wd[4], *Wm_s = wd[5];
    u32 *Wq_c = wd[6], *Wk_c = wd[7], *Wv_c = wd[8], *Wo_c = wd[9], *We_c = wd[10], *Wm_c = wd[11];
    u32 *W1 = wd[12], *Dact = wd[13], *W2 = wd[14];

    // zero qktb once (d=48..63 pad slots must be 0; qkv only writes d<48)
    hipMemsetAsync(qktb, 0, (size_t)32 * N_ * 64 * sizeof(ush), stream);

    {
        WCArgs a;
        for (int i = 0; i < 15; ++i) {
            a.src[i] = (const float*)d_in[14 + i];
            a.dst[i] = wd[i];
            a.n[i]   = wn[i];
            a.scale[i] = 1.f;
        }
        a.scale[0] = 0.14433756729740643f;  // Wq_s: fold 1/sqrt(48)
        a.scale[6] = 0.14433756729740643f;  // Wq_c
        wconv_kernel<<<dim3(1024, 15), 256, 0, stream>>>(a);
    }

    dim3 gln(N_ / 32, B_);
    dim3 gtr(N_ / 32, C_ / 32, B_ * 3);
    dim3 gat(2048);
    dim3 gar(N_ / 64, B_ * HEADS_);
    dim3 ggr(N_, B_);
    dim3 gqkv(96, 6, B_);
    dim3 gwe(96, 4, B_);
    dim3 gg128(96, 2, B_);
    dim3 gg512(96, 8, B_);

    // ---- Phase A: self attention block ----
    ln_kernel<<<gln, 256, 0, stream>>>(q_in, g1, b1, nx, nx_s);
    {
        QKVArgs A{Wq_s, Wk_s, Wv_s, nx_s, nx_s, nx_s};
        qkv_kernel<<<gqkv, 256, 0, stream>>>(A, qkvb, qktb);
    }
    transpose_kernel<<<gtr, 256, 0, stream>>>(nx, t1);
    attn_mfma_kernel<<<gat, 256, 0, stream>>>(qkvb, qktb, pacc, pml);
    attn_reduce_kernel<<<gar, 256, 0, stream>>>(pacc, pml, ao_s);
    graph_kernel<<<ggr, 256, 0, stream>>>(t1, t1, idx_s, gbuf_s);
    wowe_kernel<<<gwe, 256, 0, stream>>>(Wo_s, ao_s, We_s, gbuf_s, f12_s);
    gemm_kernel2<0,0,true><<<gg128, 256, 0, stream>>>(Wm_s, 256, f12_s, q_in, qa, nullptr, 128, 0, 256);

    // ---- Phase B: cross attention block ----
    ln_kernel<<<gln, 256, 0, stream>>>(qa,   gq, bq, nx, nx_s);
    ln_kernel<<<gln, 256, 0, stream>>>(v_in, gv, bv, nv, nv_s);
    {
        QKVArgs A{Wq_c, Wk_c, Wv_c, nx_s, nv_s, nv_s};
        qkv_kernel<<<gqkv, 256, 0, stream>>>(A, qkvb, qktb);
    }
    transpose_kernel<<<gtr, 256, 0, stream>>>(nx, t1);
    transpose_kernel<<<gtr, 256, 0, stream>>>(nv, t2);
    attn_mfma_kernel<<<gat, 256, 0, stream>>>(qkvb, qktb, pacc, pml);
    attn_reduce_kernel<<<gar, 256, 0, stream>>>(pacc, pml, ao_s);
    graph_kernel<<<ggr, 256, 0, stream>>>(t1, t2, idx_c, gbuf_s);
    wowe_kernel<<<gwe, 256, 0, stream>>>(Wo_c, ao_s, We_c, gbuf_s, f12_s);
    gemm_kernel2<0,0,true><<<gg128, 256, 0, stream>>>(Wm_c, 256, f12_s, qa, qb, nullptr, 128, 0, 256);

    // ---- Phase C: vector MLP ----
    ln_kernel<<<gln, 256, 0, stream>>>(qb, g2, b2, nx, nx_s);
    gemm_kernel2<0,2,false><<<gg512, 256, 0, stream>>>(W1, 128, nx_s, nullptr, h1, h1_s, 512, 0, 128);
    gemm_kernel2<0,0,false><<<gg512, 256, 0, stream>>>(Dact, 512, h1_s, nullptr, hd, nullptr, 512, 0, 512);
    leaky_kernel<<<dim3((B_ * HID_ * N_) / 256), 256, 0, stream>>>(h1, hd, h1_s);
    gemm_kernel2<0,0,true><<<gg128, 256, 0, stream>>>(W2, 512, h1_s, qb, out, nullptr, 128, 0, 512);
}

// Round 11
// 302.973 us; speedup vs baseline: 1.2157x; 1.2157x over previous
//
#include <hip/hip_runtime.h>
#include <math.h>

#define B_    2
#define C_    128
#define N_    2048
#define HID_  512
#define HEADS_ 8
#define EPS_  1e-6f
#define NS_   0.2f
#define KSPLIT 8

typedef __attribute__((ext_vector_type(8))) short short8v;  // 8 bf16
typedef __attribute__((ext_vector_type(4))) float f32x4;
typedef unsigned short ush;
typedef unsigned int u32;

__device__ inline ush f2bf(float f) {
    unsigned u = __float_as_uint(f);
    u += 0x7FFF + ((u >> 16) & 1);          // round-to-nearest-even
    return (ush)(u >> 16);
}
__device__ inline float bf2f(ush u) { return __uint_as_float((u32)u << 16); }

// pack float -> (hi bf16 << 16) | lo bf16, with hi+lo ~ x to ~2^-17 rel
__device__ inline u32 splitpack(float x) {
    ush hi = f2bf(x);
    float hf = __uint_as_float((u32)hi << 16);
    ush lo = f2bf(x - hf);
    return ((u32)hi << 16) | (u32)lo;
}

__device__ inline void unpack16(const u32* buf, short8v& h0, short8v& h1,
                                short8v& l0, short8v& l1) {
    ush h[16], l[16];
    #pragma unroll
    for (int j = 0; j < 16; ++j) { u32 u = buf[j]; h[j] = (ush)(u >> 16); l[j] = (ush)(u & 0xffff); }
    h0 = *(short8v*)&h[0]; h1 = *(short8v*)&h[8];
    l0 = *(short8v*)&l[0]; l1 = *(short8v*)&l[8];
}

__device__ inline void unpack_hi(const u32* buf, short8v& h0, short8v& h1) {
    ush h[16];
    #pragma unroll
    for (int j = 0; j < 16; ++j) h[j] = (ush)(buf[j] >> 16);
    h0 = *(short8v*)&h[0]; h1 = *(short8v*)&h[8];
}

// ---------------------------------------------------------------------------
// vec_layernorm: writes fp32 y AND split plane ysp (round-8 verified version)
// ---------------------------------------------------------------------------
__global__ __launch_bounds__(256) void ln_kernel(const float* __restrict__ x,
        const float* __restrict__ gma, const float* __restrict__ bta,
        float* __restrict__ y, u32* __restrict__ ysp)
{
    __shared__ float norms[128][32];
    __shared__ float red1[8][32];
    __shared__ float red2[8][32];
    const int b  = blockIdx.y;
    const int n0 = blockIdx.x * 32;
    const int nn = threadIdx.x & 31;
    const int cg = threadIdx.x >> 5;

    float s1 = 0.f, s2 = 0.f;
    for (int it = 0; it < 16; ++it) {
        int c = it * 8 + cg;
        size_t base = ((size_t)(b * C_ + c) * 3) * N_ + n0 + nn;
        float x0 = x[base], x1 = x[base + N_], x2 = x[base + 2 * N_];
        float nr = sqrtf(x0 * x0 + x1 * x1 + x2 * x2 + EPS_);
        norms[c][nn] = nr;
        s1 += nr; s2 += nr * nr;
    }
    red1[cg][nn] = s1; red2[cg][nn] = s2;
    __syncthreads();
    float S1 = 0.f, S2 = 0.f;
    #pragma unroll
    for (int g = 0; g < 8; ++g) { S1 += red1[g][nn]; S2 += red2[g][nn]; }
    float mu   = S1 * (1.f / 128.f);
    float var  = S2 * (1.f / 128.f) - mu * mu;
    float rstd = rsqrtf(var + EPS_);

    for (int it = 0; it < 16; ++it) {
        int c = it * 8 + cg;
        float nr = norms[c][nn];
        float ln = (nr - mu) * rstd * gma[c] + bta[c];
        float sc = ln / (nr + EPS_);
        size_t base = ((size_t)(b * C_ + c) * 3) * N_ + n0 + nn;
        float y0 = x[base] * sc, y1 = x[base + N_] * sc, y2 = x[base + 2 * N_] * sc;
        y[base]          = y0;
        y[base + N_]     = y1;
        y[base + 2 * N_] = y2;
        ysp[base]          = splitpack(y0);
        ysp[base + N_]     = splitpack(y1);
        ysp[base + 2 * N_] = splitpack(y2);
    }
}

// ---------------------------------------------------------------------------
// weight split-conversion: 15 weights, one launch (with optional pre-scale)
// ---------------------------------------------------------------------------
struct WCArgs { const float* src[15]; u32* dst[15]; int n[15]; float scale[15]; };
__global__ __launch_bounds__(256) void wconv_kernel(WCArgs a)
{
    const int w = blockIdx.y;
    const int i = blockIdx.x * 256 + threadIdx.x;
    if (i < a.n[w]) a.dst[w][i] = splitpack(a.src[w][i] * a.scale[w]);
}

// ---------------------------------------------------------------------------
// bf16 MFMA GEMM core. SPLIT=true: Wh·Xh + Wh·Xl + Wl·Xh (fp32-quality).
// SPLIT=false: Wh·Xh only. 64x64 tile, K-step 64, 4 waves. LDS XOR-swizzled.
// XMODE 0: X[(b*K + c)*M + m]   XMODE 1: X[((b*N+n)*3+t)*K + c], m = t*N+n
// OMODE 0: fp32 (+Z)  1: split u32  2: both  3: bf16  4: qkv fragment-major
//   (Q/K -> Ytr 1KB MFMA-fragment blocks; V -> Ybf 1KB fragment blocks)
// ---------------------------------------------------------------------------
template <int XMODE, int OMODE, bool SPLIT>
__device__ __forceinline__ void gemm_tile(
    const u32* __restrict__ Wsp, int wstride,
    const u32* __restrict__ Xsp, int K,
    const float* __restrict__ Z, float* __restrict__ Y, u32* __restrict__ Ysp,
    ush* __restrict__ Ybf, ush* __restrict__ Ytr,
    int b, int m0, int o0loc, int oglob, int Ostr,
    ush (*Wh)[64], ush (*Wl)[64], ush (*Xh)[64], ush (*Xl)[64])
{
    const int M = 3 * N_;
    const int tid = threadIdx.x;
    const int lane = tid & 63, wv = tid >> 6;
    const int col = lane & 15, grp = lane >> 4;
    const int wo = wv >> 1, wm = wv & 1;

    f32x4 acc[2][2];
    #pragma unroll
    for (int i = 0; i < 2; ++i)
        #pragma unroll
        for (int j = 0; j < 2; ++j) { f32x4 z = {0.f,0.f,0.f,0.f}; acc[i][j] = z; }

    for (int kk = 0; kk < K; kk += 64) {
        // ---- stage W tile (64 o x 64 k) ----
        {
            const int o = tid >> 2, kg = tid & 3;
            const u32* src = Wsp + (size_t)(o0loc + o) * wstride + kk + kg * 16;
            u32 buf[16];
            #pragma unroll
            for (int j = 0; j < 4; ++j) *(uint4*)&buf[j * 4] = *(const uint4*)(src + j * 4);
            const int s0 = ((kg * 2)     ^ (o & 7)) << 3;
            const int s1 = ((kg * 2 + 1) ^ (o & 7)) << 3;
            if (SPLIT) {
                short8v h0, h1, l0, l1; unpack16(buf, h0, h1, l0, l1);
                *(short8v*)&Wh[o][s0] = h0; *(short8v*)&Wh[o][s1] = h1;
                *(short8v*)&Wl[o][s0] = l0; *(short8v*)&Wl[o][s1] = l1;
            } else {
                short8v h0, h1; unpack_hi(buf, h0, h1);
                *(short8v*)&Wh[o][s0] = h0; *(short8v*)&Wh[o][s1] = h1;
            }
        }
        // ---- stage X tile (64 k x 64 m), stored transposed Xs[m][k] ----
        if (XMODE == 0) {
            const int m = lane, kq = wv;
            const u32* src = Xsp + ((size_t)b * K + kk + kq * 16) * M + m0 + m;
            u32 buf[16];
            #pragma unroll
            for (int j = 0; j < 16; ++j) buf[j] = src[(size_t)j * M];
            const int s0 = ((kq * 2)     ^ (m & 7)) << 3;
            const int s1 = ((kq * 2 + 1) ^ (m & 7)) << 3;
            if (SPLIT) {
                short8v h0, h1, l0, l1; unpack16(buf, h0, h1, l0, l1);
                *(short8v*)&Xh[m][s0] = h0; *(short8v*)&Xh[m][s1] = h1;
                *(short8v*)&Xl[m][s0] = l0; *(short8v*)&Xl[m][s1] = l1;
            } else {
                short8v h0, h1; unpack_hi(buf, h0, h1);
                *(short8v*)&Xh[m][s0] = h0; *(short8v*)&Xh[m][s1] = h1;
            }
        } else {
            const int m = tid >> 2, kg = tid & 3;
            const int mg = m0 + m;
            const int n = mg & (N_ - 1), t = mg >> 11;
            const u32* src = Xsp + ((size_t)(b * N_ + n) * 3 + t) * K + kk + kg * 16;
            u32 buf[16];
            #pragma unroll
            for (int j = 0; j < 4; ++j) *(uint4*)&buf[j * 4] = *(const uint4*)(src + j * 4);
            const int s0 = ((kg * 2)     ^ (m & 7)) << 3;
            const int s1 = ((kg * 2 + 1) ^ (m & 7)) << 3;
            if (SPLIT) {
                short8v h0, h1, l0, l1; unpack16(buf, h0, h1, l0, l1);
                *(short8v*)&Xh[m][s0] = h0; *(short8v*)&Xh[m][s1] = h1;
                *(short8v*)&Xl[m][s0] = l0; *(short8v*)&Xl[m][s1] = l1;
            } else {
                short8v h0, h1; unpack_hi(buf, h0, h1);
                *(short8v*)&Xh[m][s0] = h0; *(short8v*)&Xh[m][s1] = h1;
            }
        }
        __syncthreads();
        // ---- MFMAs per K-step: 8 (hi-only) or 24 (split) ----
        #pragma unroll
        for (int kc = 0; kc < 2; ++kc) {
            const int sk = ((kc * 4 + grp) ^ (col & 7)) << 3;
            short8v ah0 = *(const short8v*)&Wh[wo * 32 + col][sk];
            short8v ah1 = *(const short8v*)&Wh[wo * 32 + 16 + col][sk];
            short8v xh0 = *(const short8v*)&Xh[wm * 32 + col][sk];
            short8v xh1 = *(const short8v*)&Xh[wm * 32 + 16 + col][sk];
            acc[0][0] = __builtin_amdgcn_mfma_f32_16x16x32_bf16(ah0, xh0, acc[0][0], 0, 0, 0);
            acc[0][1] = __builtin_amdgcn_mfma_f32_16x16x32_bf16(ah0, xh1, acc[0][1], 0, 0, 0);
            acc[1][0] = __builtin_amdgcn_mfma_f32_16x16x32_bf16(ah1, xh0, acc[1][0], 0, 0, 0);
            acc[1][1] = __builtin_amdgcn_mfma_f32_16x16x32_bf16(ah1, xh1, acc[1][1], 0, 0, 0);
            if (SPLIT) {
                short8v al0 = *(const short8v*)&Wl[wo * 32 + col][sk];
                short8v al1 = *(const short8v*)&Wl[wo * 32 + 16 + col][sk];
                short8v xl0 = *(const short8v*)&Xl[wm * 32 + col][sk];
                short8v xl1 = *(const short8v*)&Xl[wm * 32 + 16 + col][sk];
                acc[0][0] = __builtin_amdgcn_mfma_f32_16x16x32_bf16(ah0, xl0, acc[0][0], 0, 0, 0);
                acc[0][1] = __builtin_amdgcn_mfma_f32_16x16x32_bf16(ah0, xl1, acc[0][1], 0, 0, 0);
                acc[1][0] = __builtin_amdgcn_mfma_f32_16x16x32_bf16(ah1, xl0, acc[1][0], 0, 0, 0);
                acc[1][1] = __builtin_amdgcn_mfma_f32_16x16x32_bf16(ah1, xl1, acc[1][1], 0, 0, 0);
                acc[0][0] = __builtin_amdgcn_mfma_f32_16x16x32_bf16(al0, xh0, acc[0][0], 0, 0, 0);
                acc[0][1] = __builtin_amdgcn_mfma_f32_16x16x32_bf16(al0, xh1, acc[0][1], 0, 0, 0);
                acc[1][0] = __builtin_amdgcn_mfma_f32_16x16x32_bf16(al1, xh0, acc[1][0], 0, 0, 0);
                acc[1][1] = __builtin_amdgcn_mfma_f32_16x16x32_bf16(al1, xh1, acc[1][1], 0, 0, 0);
            }
        }
        __syncthreads();
    }
    // ---- epilogue ----
    #pragma unroll
    for (int of = 0; of < 2; ++of) {
        #pragma unroll
        for (int r = 0; r < 4; ++r) {
            const int o = oglob + wo * 32 + of * 16 + grp * 4 + r;
            #pragma unroll
            for (int mf = 0; mf < 2; ++mf) {
                const int mloc = m0 + wm * 32 + mf * 16 + col;
                const size_t idx = ((size_t)b * Ostr + o) * M + mloc;
                float v = acc[of][mf][r];
                if (OMODE == 0 || OMODE == 2) {
                    if (Z) v += Z[idx];
                    Y[idx] = v;
                }
                if (OMODE == 1 || OMODE == 2) Ysp[idx] = splitpack(v);
                if (OMODE == 3) Ybf[idx] = f2bf(v);
                if (OMODE == 4) {
                    ush bv = f2bf(v);
                    const int t = mloc >> 11, n = mloc & (N_ - 1);
                    const int h = (o >> 4) & 7, cl = o & 15;
                    const int d = cl * 3 + t;
                    if (o >= 256) {
                        // V fragment-major: plane (b*8+h), 1KB blocks
                        const int kt = n >> 6, hh = (n >> 5) & 1, db = d >> 4;
                        const size_t idx2 = ((size_t)(b * 8 + h) * 192
                                           + (kt * 2 + hh) * 3 + db) * 512
                                          + (((n >> 3) & 3) * 16 + (d & 15)) * 8 + (n & 7);
                        Ybf[idx2] = bv;
                    } else {
                        // Q/K fragment-major: plane (isK*16 + b*8 + h), 1KB blocks
                        const int isK = (o >> 7) & 1;
                        const int qg = n >> 4, half = d >> 5;
                        const size_t idx2 = ((size_t)(isK * 16 + b * 8 + h) * 256
                                           + qg * 2 + half) * 512
                                          + (((d >> 3) & 3) * 16 + (n & 15)) * 8 + (d & 7);
                        Ytr[idx2] = bv;
                    }
                }
            }
        }
    }
}

template <int XMODE, int OMODE, bool SPLIT>
__global__ __launch_bounds__(256) void gemm_kernel2(
    const u32* __restrict__ Wsp, int wstride,
    const u32* __restrict__ Xsp,
    const float* __restrict__ Z,
    float* __restrict__ Y, u32* __restrict__ Ysp,
    int Ostr, int obase, int K)
{
    if (SPLIT) {
        __shared__ __align__(16) ush Wh[64][64];
        __shared__ __align__(16) ush Wl[64][64];
        __shared__ __align__(16) ush Xh[64][64];
        __shared__ __align__(16) ush Xl[64][64];
        gemm_tile<XMODE, OMODE, true>(Wsp, wstride, Xsp, K, Z, Y, Ysp, nullptr, nullptr,
                                blockIdx.z, blockIdx.x * 64,
                                blockIdx.y * 64, obase + blockIdx.y * 64, Ostr,
                                Wh, Wl, Xh, Xl);
    } else {
        __shared__ __align__(16) ush Wh[64][64];
        __shared__ __align__(16) ush Xh[64][64];
        gemm_tile<XMODE, OMODE, false>(Wsp, wstride, Xsp, K, Z, Y, Ysp, nullptr, nullptr,
                                blockIdx.z, blockIdx.x * 64,
                                blockIdx.y * 64, obase + blockIdx.y * 64, Ostr,
                                Wh, nullptr, Xh, nullptr);
    }
}

struct QKVArgs {
    const u32* W0; const u32* W1; const u32* W2;
    const u32* X0; const u32* X1; const u32* X2;
};

// fused Q/K/V projections (hi-only): all outputs fragment-major
__global__ __launch_bounds__(256) void qkv_kernel(QKVArgs A, ush* __restrict__ Vfm,
                                                  ush* __restrict__ qktb)
{
    __shared__ __align__(16) ush Wh[64][64];
    __shared__ __align__(16) ush Xh[64][64];
    const int wi = blockIdx.y >> 1;
    const u32* W = wi == 0 ? A.W0 : (wi == 1 ? A.W1 : A.W2);
    const u32* X = wi == 0 ? A.X0 : (wi == 1 ? A.X1 : A.X2);
    gemm_tile<0, 4, false>(W, 128, X, 128, nullptr, nullptr, nullptr, Vfm, qktb,
                    blockIdx.z, blockIdx.x * 64,
                    (blockIdx.y & 1) * 64, blockIdx.y * 64, 384,
                    Wh, nullptr, Xh, nullptr);
}

// fused Wo (XMODE0, y=0,1) + We (XMODE1, y=2,3) -> f12 split (Ostr 256)
__global__ __launch_bounds__(256) void wowe_kernel(
    const u32* __restrict__ Wo, const u32* __restrict__ ao,
    const u32* __restrict__ We, const u32* __restrict__ gb,
    u32* __restrict__ f12)
{
    __shared__ __align__(16) ush Wh[64][64];
    __shared__ __align__(16) ush Xh[64][64];
    const int y = blockIdx.y;
    if (y < 2)
        gemm_tile<0, 1, false>(Wo, 128, ao, 128, nullptr, nullptr, f12, nullptr, nullptr,
                        blockIdx.z, blockIdx.x * 64, y * 64, y * 64, 256,
                        Wh, nullptr, Xh, nullptr);
    else
        gemm_tile<1, 1, false>(We, 256, gb, 256, nullptr, nullptr, f12, nullptr, nullptr,
                        blockIdx.z, blockIdx.x * 64, (y - 2) * 64, 128 + (y - 2) * 64, 256,
                        Wh, nullptr, Xh, nullptr);
}

// ---------------------------------------------------------------------------
// barrier-free split-K flash attention, XCD-chunked, fragment-major operands.
// Every Q/K/V global load = one fully-coalesced 1KB burst (lane*16B).
// ---------------------------------------------------------------------------
__global__ __launch_bounds__(256) void attn_mfma_kernel(
    const ush* __restrict__ vfm, const ush* __restrict__ qktb,
    ush* __restrict__ pacc, float* __restrict__ pml)
{
    __shared__ __align__(16) ush Pl[4][2][16][64];   // 16 KB

    // XCD-chunked decode: flat%8 = XCD (de-facto round-robin assignment)
    const int flat = blockIdx.x;
    const int xcd  = flat & 7;
    const int slot = flat >> 3;          // 0..255
    const int gid  = xcd * 4 + (slot >> 6);   // 0..31, 4 groups per XCD
    const int q32  = slot & 63;
    const int bh   = gid & 15;
    const int zz   = gid >> 4;           // 0..1

    const int tid = threadIdx.x;
    const int lane = tid & 63, wv = tid >> 6;
    const int col = lane & 15, grp = lane >> 4;
    const int c7  = col & 7;
    const int kz  = zz * 4 + wv;
    const int ks0 = kz * (N_ / KSPLIT);

    const ush* Qpl = qktb + (size_t)bh * 131072;         // 256 blocks * 512
    const ush* Kpl = qktb + (size_t)(16 + bh) * 131072;
    const ush* Vpl = vfm  + (size_t)bh * 98304;          // 192 blocks * 512

    short8v qf[2][2];
    #pragma unroll
    for (int qi = 0; qi < 2; ++qi) {
        const int qg = q32 * 2 + qi;
        qf[qi][0] = *(const short8v*)(Qpl + ((size_t)qg * 2 + 0) * 512 + lane * 8);
        qf[qi][1] = *(const short8v*)(Qpl + ((size_t)qg * 2 + 1) * 512 + lane * 8);
    }

    f32x4 acc[2][3];
    #pragma unroll
    for (int qi = 0; qi < 2; ++qi)
        #pragma unroll
        for (int db = 0; db < 3; ++db) { f32x4 z = {0.f,0.f,0.f,0.f}; acc[qi][db] = z; }
    float m_i[2] = {0.f, 0.f};
    float l_l[2] = {0.f, 0.f};     // per-lane partial sums

    const int NT = (N_ / KSPLIT) / 64;    // 4 tiles of 64 keys
    for (int mt = 0; mt < NT; ++mt) {
        const int m0 = ks0 + mt * 64;

        // K fragments: coalesced 1KB bursts
        short8v ka[4][2];
        #pragma unroll
        for (int kb = 0; kb < 4; ++kb) {
            const size_t kg = (m0 >> 4) + kb;
            ka[kb][0] = *(const short8v*)(Kpl + (kg * 2 + 0) * 512 + lane * 8);
            ka[kb][1] = *(const short8v*)(Kpl + (kg * 2 + 1) * 512 + lane * 8);
        }
        // V fragments: coalesced 1KB bursts
        const int kt = m0 >> 6;
        short8v vf[2][3];
        #pragma unroll
        for (int hh = 0; hh < 2; ++hh)
            #pragma unroll
            for (int db = 0; db < 3; ++db)
                vf[hh][db] = *(const short8v*)(Vpl + (size_t)((kt * 2 + hh) * 3 + db) * 512 + lane * 8);

        // ---- QK^T (swapped): sf[qi][kb] rows = keys, col = query ----
        f32x4 sf[2][4];
        __builtin_amdgcn_s_setprio(1);
        #pragma unroll
        for (int qi = 0; qi < 2; ++qi)
            #pragma unroll
            for (int kb = 0; kb < 4; ++kb) {
                f32x4 z = {0.f, 0.f, 0.f, 0.f};
                z = __builtin_amdgcn_mfma_f32_16x16x32_bf16(ka[kb][0], qf[qi][0], z, 0, 0, 0);
                z = __builtin_amdgcn_mfma_f32_16x16x32_bf16(ka[kb][1], qf[qi][1], z, 0, 0, 0);
                sf[qi][kb] = z;
            }
        __builtin_amdgcn_s_setprio(0);

        // ---- exp with current (lazy) max; P -> per-wave LDS ----
        #pragma unroll
        for (int qi = 0; qi < 2; ++qi) {
            float psum = 0.f;
            #pragma unroll
            for (int kb = 0; kb < 4; ++kb) {
                float e0 = __expf(sf[qi][kb][0] - m_i[qi]);
                float e1 = __expf(sf[qi][kb][1] - m_i[qi]);
                float e2 = __expf(sf[qi][kb][2] - m_i[qi]);
                float e3 = __expf(sf[qi][kb][3] - m_i[qi]);
                psum += (e0 + e1) + (e2 + e3);
                u32 r0, r1;
                asm("v_cvt_pk_bf16_f32 %0, %1, %2" : "=v"(r0) : "v"(e0), "v"(e1));
                asm("v_cvt_pk_bf16_f32 %0, %1, %2" : "=v"(r1) : "v"(e2), "v"(e3));
                const int un = (4 * kb + grp) ^ (c7 << 1);
                uint2 pk2; pk2.x = r0; pk2.y = r1;
                *(uint2*)&Pl[wv][qi][col][un << 2] = pk2;
            }
            l_l[qi] += psum;
        }

        // ---- PV ----
        __builtin_amdgcn_s_setprio(1);
        #pragma unroll
        for (int qi = 0; qi < 2; ++qi)
            #pragma unroll
            for (int hh = 0; hh < 2; ++hh) {
                const int ur = (8 * hh + 2 * grp) ^ (c7 << 1);
                short8v pf = *(const short8v*)&Pl[wv][qi][col][ur << 2];
                #pragma unroll
                for (int db = 0; db < 3; ++db)
                    acc[qi][db] = __builtin_amdgcn_mfma_f32_16x16x32_bf16(vf[hh][db], pf, acc[qi][db], 0, 0, 0);
            }
        __builtin_amdgcn_s_setprio(0);

        // ---- post-PV lazy max update ----
        #pragma unroll
        for (int qi = 0; qi < 2; ++qi) {
            float pmax = -1e30f;
            #pragma unroll
            for (int kb = 0; kb < 4; ++kb)
                #pragma unroll
                for (int r = 0; r < 4; ++r) pmax = fmaxf(pmax, sf[qi][kb][r]);
            pmax = fmaxf(pmax, __shfl_xor(pmax, 16, 64));
            pmax = fmaxf(pmax, __shfl_xor(pmax, 32, 64));
            if (!__all(pmax - m_i[qi] <= 8.0f)) {
                float mnew = fmaxf(m_i[qi], pmax);
                float sc = __expf(m_i[qi] - mnew);
                l_l[qi] *= sc;
                #pragma unroll
                for (int db = 0; db < 3; ++db) {
                    acc[qi][db][0] *= sc; acc[qi][db][1] *= sc;
                    acc[qi][db][2] *= sc; acc[qi][db][3] *= sc;
                }
                m_i[qi] = mnew;
            }
        }
    }

    // ---- partial epilogue ----
    const int ntile = q32 >> 1, qh = q32 & 1;
    const size_t pb = (size_t)(kz * 16 + bh) * 32 + ntile;
    #pragma unroll
    for (int qi = 0; qi < 2; ++qi) {
        float l = l_l[qi];
        l += __shfl_xor(l, 16, 64);
        l += __shfl_xor(l, 32, 64);
        const int q = qh * 32 + qi * 16 + col;
        #pragma unroll
        for (int db = 0; db < 3; ++db)
            #pragma unroll
            for (int r = 0; r < 4; ++r) {
                int d = db * 16 + grp * 4 + r;
                pacc[pb * 3072 + d * 64 + q] = f2bf(acc[qi][db][r]);
            }
        if (grp == 0) {
            pml[pb * 128 + q]      = m_i[qi];
            pml[pb * 128 + 64 + q] = l;
        }
    }
}

// ---------------------------------------------------------------------------
// split-K reduce: combine KSPLIT partials -> split u32 output
// ---------------------------------------------------------------------------
__global__ __launch_bounds__(256) void attn_reduce_kernel(
    const ush* __restrict__ pacc, const float* __restrict__ pml,
    u32* __restrict__ out_sp)
{
    const int nt = blockIdx.x, bh = blockIdx.y;
    const int b = bh >> 3, h = bh & 7;
    const int tid = threadIdx.x;
    const int q = tid & 63, dg = tid >> 6;

    size_t pb[KSPLIT];
    float m[KSPLIT], l[KSPLIT];
    #pragma unroll
    for (int kz = 0; kz < KSPLIT; ++kz) {
        pb[kz] = (size_t)(kz * 16 + bh) * 32 + nt;
        m[kz] = pml[pb[kz] * 128 + q];
        l[kz] = pml[pb[kz] * 128 + 64 + q];
    }
    float ms = -1e30f;
    #pragma unroll
    for (int kz = 0; kz < KSPLIT; ++kz) ms = fmaxf(ms, m[kz]);
    float w[KSPLIT], ls = 0.f;
    #pragma unroll
    for (int kz = 0; kz < KSPLIT; ++kz) { w[kz] = __expf(m[kz] - ms); ls += l[kz] * w[kz]; }
    const float inv = 1.f / ls;

    const size_t hb = ((size_t)(b * C_ + h * 16)) * 3 * N_;
    #pragma unroll
    for (int j = 0; j < 12; ++j) {
        int d = dg * 12 + j;
        float o = 0.f;
        #pragma unroll
        for (int kz = 0; kz < KSPLIT; ++kz)
            o += bf2f(pacc[pb[kz] * 3072 + d * 64 + q]) * w[kz];
        out_sp[hb + (size_t)d * N_ + nt * 64 + q] = splitpack(o * inv);
    }
}

// ---------------------------------------------------------------------------
// transpose (B,C,3,N) -> (B,N,3,C) fp32
// ---------------------------------------------------------------------------
__global__ __launch_bounds__(256) void transpose_kernel(const float* __restrict__ x,
                                                        float* __restrict__ y)
{
    __shared__ float tile[32][33];
    const int z = blockIdx.z;
    const int b = z / 3, t = z % 3;
    const int n0 = blockIdx.x * 32, c0 = blockIdx.y * 32;
    const int tx = threadIdx.x & 31, ty = threadIdx.x >> 5;
    #pragma unroll
    for (int p = 0; p < 4; ++p) {
        int c = c0 + ty + p * 8;
        tile[ty + p * 8][tx] = x[((size_t)(b * C_ + c) * 3 + t) * N_ + n0 + tx];
    }
    __syncthreads();
    #pragma unroll
    for (int p = 0; p < 4; ++p) {
        int n = n0 + ty + p * 8;
        y[((size_t)(b * N_ + n) * 3 + t) * C_ + c0 + tx] = tile[tx][ty + p * 8];
    }
}

// ---------------------------------------------------------------------------
// graph attention: fp32 in (B,N,3,C), split u32 edge buffer out
// ---------------------------------------------------------------------------
__global__ __launch_bounds__(256) void graph_kernel(
    const float* __restrict__ tq, const float* __restrict__ tv,
    const int* __restrict__ idx, u32* __restrict__ g)
{
    __shared__ float center[384];
    __shared__ float sd[16];
    __shared__ int nbr_i[16];
    const int b = blockIdx.y, n = blockIdx.x;
    const int tid = threadIdx.x;
    const float* qrow = tq + (size_t)(b * N_ + n) * 384;
    for (int e = tid; e < 384; e += 256) center[e] = qrow[e];
    if (tid < 16) nbr_i[tid] = idx[(size_t)(b * N_ + n) * 16 + tid];
    __syncthreads();

    const int lane = tid & 63, wv = tid >> 6;
    for (int kk = 0; kk < 4; ++kk) {
        int k = wv * 4 + kk;
        const float* vrow = tv + ((size_t)b * N_ + nbr_i[k]) * 384;
        float p = 0.f;
        #pragma unroll
        for (int jj = 0; jj < 6; ++jj) {
            int e = lane + jj * 64;
            p += center[e] * vrow[e];
        }
        #pragma unroll
        for (int off = 32; off; off >>= 1) p += __shfl_down(p, off, 64);
        if (lane == 0) sd[k] = p * 0.05103103630798288f;
    }
    __syncthreads();

    float mx = -1e30f;
    #pragma unroll
    for (int k = 0; k < 16; ++k) mx = fmaxf(mx, sd[k]);
    float a[16]; float ssum = 0.f;
    #pragma unroll
    for (int k = 0; k < 16; ++k) { a[k] = __expf(sd[k] - mx); ssum += a[k]; }
    float inv = 1.f / ssum;

    for (int e = tid; e < 384; e += 256) {
        float accv = 0.f;
        #pragma unroll
        for (int k = 0; k < 16; ++k)
            accv += a[k] * tv[((size_t)b * N_ + nbr_i[k]) * 384 + e];
        accv *= inv;
        float ce = center[e];
        int t = e >> 7, c = e & 127;
        size_t gb = ((size_t)(b * N_ + n) * 3 + t) * 256;
        g[gb + c]       = splitpack(accv - ce);
        g[gb + 128 + c] = splitpack(ce);
    }
}

// ---------------------------------------------------------------------------
// vn_leaky: fp32 x,d in -> split u32 out
// ---------------------------------------------------------------------------
__global__ __launch_bounds__(256) void leaky_kernel(const float* __restrict__ x,
                                                    const float* __restrict__ d,
                                                    u32* __restrict__ y)
{
    size_t p = (size_t)blockIdx.x * 256 + threadIdx.x;
    size_t bh = p / N_, n = p % N_;
    size_t base = bh * 3 * N_ + n;
    float x0 = x[base], x1 = x[base + N_], x2 = x[base + 2 * N_];
    float d0 = d[base], d1 = d[base + N_], d2 = d[base + 2 * N_];
    float dot = x0 * d0 + x1 * d1 + x2 * d2;
    float dsq = d0 * d0 + d1 * d1 + d2 * d2;
    float f = dot / (dsq + EPS_);
    bool pos = dot >= 0.f;
    float y0 = pos ? x0 : x0 - f * d0;
    float y1 = pos ? x1 : x1 - f * d1;
    float y2 = pos ? x2 : x2 - f * d2;
    y[base]          = splitpack(NS_ * x0 + (1.f - NS_) * y0);
    y[base + N_]     = splitpack(NS_ * x1 + (1.f - NS_) * y1);
    y[base + 2 * N_] = splitpack(NS_ * x2 + (1.f - NS_) * y2);
}

// ---------------------------------------------------------------------------
extern "C" void kernel_launch(void* const* d_in, const int* in_sizes, int n_in,
                              void* d_out, int out_size, void* d_ws, size_t ws_size,
                              hipStream_t stream)
{
    const float* q_in = (const float*)d_in[0];
    const float* v_in = (const float*)d_in[1];
    const int*   idx_s = (const int*)d_in[4];
    const int*   idx_c = (const int*)d_in[5];
    const float* g1 = (const float*)d_in[6];
    const float* b1 = (const float*)d_in[7];
    const float* g2 = (const float*)d_in[8];
    const float* b2 = (const float*)d_in[9];
    const float* gq = (const float*)d_in[10];
    const float* bq = (const float*)d_in[11];
    const float* gv = (const float*)d_in[12];
    const float* bv = (const float*)d_in[13];
    float* out = (float*)d_out;
    float* ws  = (float*)d_ws;

    const size_t S1 = (size_t)B_ * C_ * 3 * N_; // 1572864 elems
    float* nx    = ws;                 // 0
    float* nv    = ws + S1;            // 1
    u32*   nx_s  = (u32*)(ws + 2*S1);  // 2
    u32*   nv_s  = (u32*)(ws + 3*S1);  // 3
    ush*   vfm   = (ush*)(ws + 4*S1);  // 4: V fragment-major, 16*98304*2B = 3MB
    ush*   qktb  = (ush*)(ws + 5*S1) + S1;  // 5.5-6.84: 32 planes * 131072 * 2B = 8MB
    u32*   ao_s  = (u32*)(ws + 7*S1);  // 7
    u32*   f12_s = (u32*)(ws + 8*S1);  // 8-9
    u32*   gbuf_s= (u32*)(ws + 10*S1); // 10-11
    float* qa    = ws + 12*S1;         // 12
    float* qb    = ws + 13*S1;         // 13
    float* t1    = ws + 14*S1;         // 14
    float* t2    = ws + 15*S1;         // 15
    u32*   wsp   = (u32*)(ws + 16*S1); // 16
    // split-K attention partials (live only attn->reduce; freed before graph/WoWe)
    ush*   pacc  = (ush*)(ws + 8*S1);  // 8-11: 4096*3072*2B = 25.2MB
    float* pml   = (float*)(ws + 2*S1);// 2:    4096*128*4B  = 2.1MB
    // phase C aliases:
    float* hd    = ws;                 // 0-3
    float* h1    = ws + 4*S1;          // 4-7
    u32*   h1_s  = (u32*)(ws + 8*S1);  // 8-11

    const int wn[15]  = {16384,16384,16384,16384,32768,32768,
                         16384,16384,16384,16384,32768,32768,
                         65536,262144,65536};
    u32* wd[15];
    {
        int off = 0;
        for (int i = 0; i < 15; ++i) { wd[i] = wsp + off; off += wn[i]; }
    }
    u32 *Wq_s = wd[0], *Wk_s = wd[1], *Wv_s = wd[2], *Wo_s = wd[3], *We_s = wd[4], *Wm_s = wd[5];
    u32 *Wq_c = wd[6], *Wk_c = wd[7], *Wv_c = wd[8], *Wo_c = wd[9], *We_c = wd[10], *Wm_c = wd[11];
    u32 *W1 = wd[12], *Dact = wd[13], *W2 = wd[14];

    // zero qktb once (d=48..63 pad slots must be 0; qkv only writes d<48)
    hipMemsetAsync(qktb, 0, (size_t)32 * 131072 * sizeof(ush), stream);

    {
        WCArgs a;
        for (int i = 0; i < 15; ++i) {
            a.src[i] = (const float*)d_in[14 + i];
            a.dst[i] = wd[i];
            a.n[i]   = wn[i];
            a.scale[i] = 1.f;
        }
        a.scale[0] = 0.14433756729740643f;  // Wq_s: fold 1/sqrt(48)
        a.scale[6] = 0.14433756729740643f;  // Wq_c
        wconv_kernel<<<dim3(1024, 15), 256, 0, stream>>>(a);
    }

    dim3 gln(N_ / 32, B_);
    dim3 gtr(N_ / 32, C_ / 32, B_ * 3);
    dim3 gat(2048);
    dim3 gar(N_ / 64, B_ * HEADS_);
    dim3 ggr(N_, B_);
    dim3 gqkv(96, 6, B_);
    dim3 gwe(96, 4, B_);
    dim3 gg128(96, 2, B_);
    dim3 gg512(96, 8, B_);

    // ---- Phase A: self attention block ----
    ln_kernel<<<gln, 256, 0, stream>>>(q_in, g1, b1, nx, nx_s);
    {
        QKVArgs A{Wq_s, Wk_s, Wv_s, nx_s, nx_s, nx_s};
        qkv_kernel<<<gqkv, 256, 0, stream>>>(A, vfm, qktb);
    }
    transpose_kernel<<<gtr, 256, 0, stream>>>(nx, t1);
    attn_mfma_kernel<<<gat, 256, 0, stream>>>(vfm, qktb, pacc, pml);
    attn_reduce_kernel<<<gar, 256, 0, stream>>>(pacc, pml, ao_s);
    graph_kernel<<<ggr, 256, 0, stream>>>(t1, t1, idx_s, gbuf_s);
    wowe_kernel<<<gwe, 256, 0, stream>>>(Wo_s, ao_s, We_s, gbuf_s, f12_s);
    gemm_kernel2<0,0,true><<<gg128, 256, 0, stream>>>(Wm_s, 256, f12_s, q_in, qa, nullptr, 128, 0, 256);

    // ---- Phase B: cross attention block ----
    ln_kernel<<<gln, 256, 0, stream>>>(qa,   gq, bq, nx, nx_s);
    ln_kernel<<<gln, 256, 0, stream>>>(v_in, gv, bv, nv, nv_s);
    {
        QKVArgs A{Wq_c, Wk_c, Wv_c, nx_s, nv_s, nv_s};
        qkv_kernel<<<gqkv, 256, 0, stream>>>(A, vfm, qktb);
    }
    transpose_kernel<<<gtr, 256, 0, stream>>>(nx, t1);
    transpose_kernel<<<gtr, 256, 0, stream>>>(nv, t2);
    attn_mfma_kernel<<<gat, 256, 0, stream>>>(vfm, qktb, pacc, pml);
    attn_reduce_kernel<<<gar, 256, 0, stream>>>(pacc, pml, ao_s);
    graph_kernel<<<ggr, 256, 0, stream>>>(t1, t2, idx_c, gbuf_s);
    wowe_kernel<<<gwe, 256, 0, stream>>>(Wo_c, ao_s, We_c, gbuf_s, f12_s);
    gemm_kernel2<0,0,true><<<gg128, 256, 0, stream>>>(Wm_c, 256, f12_s, qa, qb, nullptr, 128, 0, 256);

    // ---- Phase C: vector MLP ----
    ln_kernel<<<gln, 256, 0, stream>>>(qb, g2, b2, nx, nx_s);
    gemm_kernel2<0,2,false><<<gg512, 256, 0, stream>>>(W1, 128, nx_s, nullptr, h1, h1_s, 512, 0, 128);
    gemm_kernel2<0,0,false><<<gg512, 256, 0, stream>>>(Dact, 512, h1_s, nullptr, hd, nullptr, 512, 0, 512);
    leaky_kernel<<<dim3((B_ * HID_ * N_) / 256), 256, 0, stream>>>(h1, hd, h1_s);
    gemm_kernel2<0,0,true><<<gg128, 256, 0, stream>>>(W2, 512, h1_s, qb, out, nullptr, 128, 0, 512);
}